// Round 7
// baseline (301.439 us; speedup 1.0000x reference)
//
#include <hip/hip_runtime.h>
#include <hip/hip_fp16.h>

#define NN 50000
#define NE 600000
#define NG 3
#define D  128
#define NI 4096
#define BW 1024                         // nodes per bucket
#define NBUCK 49                        // ceil(NN/BW)
#define EPT_BIN 16
#define EPB_BIN (256 * EPT_BIN)         // 4096 edges per block
#define NBLK_BIN ((NE + EPB_BIN - 1) / EPB_BIN)   // 147
#define XCVT_BLKS 3125                  // NN*D/8 threads, 8 floats each
#define WCVT_BLKS 48
#define CNT_BLKS (NBLK_BIN * NG)        // 441

typedef _Float16 half8 __attribute__((ext_vector_type(8)));
typedef float floatx4 __attribute__((ext_vector_type(4)));

static __device__ __forceinline__ float wextract(unsigned int v) {
  unsigned short u = (unsigned short)(v >> 16);
  _Float16 h;
  __builtin_memcpy(&h, &u, 2);
  return (float)h;
}

static __device__ __forceinline__ unsigned int packsw(int s, float w) {
  _Float16 h = (_Float16)w;
  unsigned short u;
  __builtin_memcpy(&u, &h, 2);
  return (unsigned int)s | ((unsigned int)u << 16);
}

// ---------------- fused prep: xcvt + wcvt + count ----------------

__global__ __launch_bounds__(256) void prep_kernel(
    const float* __restrict__ x, __half* __restrict__ xh,
    const float* __restrict__ W0, const float* __restrict__ W1, const float* __restrict__ W2,
    const float* __restrict__ W3, const float* __restrict__ W4, const float* __restrict__ W5,
    __half* __restrict__ Wf,
    const int* __restrict__ e0, const int* __restrict__ e1, const int* __restrict__ e2,
    int* __restrict__ bucketCnt) {
  __shared__ int cnt[NBUCK];
  int blk = blockIdx.x;
  int tid = threadIdx.x;
  if (blk < XCVT_BLKS) {
    // x -> fp16, 8 floats per thread (exactly NN*D/8 threads)
    int i = blk * 256 + tid;
    size_t base = (size_t)i * 8;
    float4 v0 = *(const float4*)&x[base];
    float4 v1 = *(const float4*)&x[base + 4];
    half8 h;
    h[0] = (_Float16)v0.x; h[1] = (_Float16)v0.y; h[2] = (_Float16)v0.z; h[3] = (_Float16)v0.w;
    h[4] = (_Float16)v1.x; h[5] = (_Float16)v1.y; h[6] = (_Float16)v1.z; h[7] = (_Float16)v1.w;
    *(half8*)&xh[base] = h;
  } else if (blk < XCVT_BLKS + WCVT_BLKS) {
    // weights -> fp16 fragment order: element = W[k=ks*32+(lane>>4)*8+j][n=tt*16+(lane&15)]
    const float* Wm[6] = {W0, W1, W2, W3, W4, W5};
    int t = (blk - XCVT_BLKS) * 256 + tid;     // 0 .. 6*2048-1
    int mat = t >> 11;
    int fr = (t >> 6) & 31;
    int lane = t & 63;
    int tt = fr >> 2, ks = fr & 3;
    int n = tt * 16 + (lane & 15);
    int kb = ks * 32 + (lane >> 4) * 8;
    const float* W = Wm[mat];
#pragma unroll
    for (int j = 0; j < 8; j++)
      Wf[(size_t)t * 8 + j] = __float2half(W[(kb + j) * 128 + n]);
  } else {
    // bucket-count histogram
    int cb = blk - XCVT_BLKS - WCVT_BLKS;
    int g = cb / NBLK_BIN, eb = cb % NBLK_BIN;
    const int* ei = (g == 0) ? e0 : ((g == 1) ? e1 : e2);
    if (tid < NBUCK) cnt[tid] = 0;
    __syncthreads();
    int base = eb * EPB_BIN;
#pragma unroll
    for (int i = 0; i < EPT_BIN; i++) {
      int e = base + tid + i * 256;
      if (e < NE) atomicAdd(&cnt[ei[NE + e] >> 10], 1);
    }
    __syncthreads();
    if (tid < NBUCK) atomicAdd(&bucketCnt[g * NBUCK + tid], cnt[tid]);
  }
}

__global__ void bscan_kernel(const int* __restrict__ bucketCnt, int* __restrict__ bucketBase,
                             int* __restrict__ cursor, int* __restrict__ rp) {
  int g = threadIdx.x;
  if (g >= NG) return;
  int run = 0;
  for (int b = 0; b < NBUCK; b++) {
    int c = bucketCnt[g * NBUCK + b];
    bucketBase[g * NBUCK + b] = run;
    cursor[g * NBUCK + b] = run;
    run += c;
  }
  rp[g * (NN + 1) + NN] = NE;
}

__global__ __launch_bounds__(256) void bin_kernel(const int* __restrict__ e0,
    const int* __restrict__ e1, const int* __restrict__ e2,
    int* __restrict__ cursor, unsigned int* __restrict__ binned) {
  __shared__ int cnt[NBUCK];
  __shared__ int base[NBUCK];
  int g = blockIdx.y;
  const int* ei = (g == 0) ? e0 : ((g == 1) ? e1 : e2);
  int tid = threadIdx.x;
  if (tid < NBUCK) cnt[tid] = 0;
  __syncthreads();
  int estart = blockIdx.x * EPB_BIN;
  int src[EPT_BIN], dst[EPT_BIN], rk[EPT_BIN];
#pragma unroll
  for (int i = 0; i < EPT_BIN; i++) {
    int e = estart + tid + i * 256;
    if (e < NE) {
      src[i] = ei[e];
      dst[i] = ei[NE + e];
      rk[i] = atomicAdd(&cnt[dst[i] >> 10], 1);
    } else {
      rk[i] = -1;
    }
  }
  __syncthreads();
  if (tid < NBUCK) base[tid] = (cnt[tid] > 0) ? atomicAdd(&cursor[g * NBUCK + tid], cnt[tid]) : 0;
  __syncthreads();
#pragma unroll
  for (int i = 0; i < EPT_BIN; i++) {
    if (rk[i] >= 0) {
      int b = dst[i] >> 10;
      binned[(size_t)g * NE + base[b] + rk[i]] =
          (unsigned int)src[i] | ((unsigned int)dst[i] << 16);
    }
  }
}

// phase 1: per-bucket degree histogram -> rp (global row ptr) + dinv
__global__ __launch_bounds__(256) void csr_kernel(const unsigned int* __restrict__ binned,
    const int* __restrict__ bucketBase, const int* __restrict__ bucketCnt,
    int* __restrict__ rp, float* __restrict__ dinv) {
  __shared__ int deg[BW];
  __shared__ int wsum[4];
  int g = blockIdx.y, b = blockIdx.x;
  int tid = threadIdx.x;
  int node0 = b * BW;
  int bb = bucketBase[g * NBUCK + b];
  int total = bucketCnt[g * NBUCK + b];
  const unsigned int* bp = binned + (size_t)g * NE + bb;
  for (int i = tid; i < BW; i += 256) deg[i] = 0;
  __syncthreads();
  for (int e = tid; e < total; e += 256) {
    unsigned int p = bp[e];
    atomicAdd(&deg[(int)(p >> 16) - node0], 1);
  }
  __syncthreads();
  int d0 = deg[tid * 4], d1 = deg[tid * 4 + 1], d2 = deg[tid * 4 + 2], d3 = deg[tid * 4 + 3];
  int s = d0 + d1 + d2 + d3;
  int lane = tid & 63;
  int incl = s;
#pragma unroll
  for (int off = 1; off < 64; off <<= 1) {
    int n = __shfl_up(incl, off, 64);
    if (lane >= off) incl += n;
  }
  if (lane == 63) wsum[tid >> 6] = incl;
  __syncthreads();
  int wbase = 0;
#pragma unroll
  for (int w = 0; w < 4; w++)
    if (w < (tid >> 6)) wbase += wsum[w];
  int ex = wbase + incl - s;
  int exs[4] = {ex, ex + d0, ex + d0 + d1, ex + d0 + d1 + d2};
  int ds[4] = {d0, d1, d2, d3};
#pragma unroll
  for (int k = 0; k < 4; k++) {
    int node = node0 + tid * 4 + k;
    if (node < NN) {
      rp[g * (NN + 1) + node] = bb + exs[k];
      dinv[g * NN + node] = rsqrtf((float)ds[k] + 1.0f);   // deg incl. self loop
    }
  }
}

// phase 2: scatter packed (src | fp16(dinv[src])) into bucket-private col region
__global__ __launch_bounds__(256) void fillp_kernel(const unsigned int* __restrict__ binned,
    const int* __restrict__ bucketBase, const int* __restrict__ bucketCnt,
    const int* __restrict__ rp, const float* __restrict__ dinv,
    unsigned int* __restrict__ colp) {
  __shared__ int cur[BW];
  int g = blockIdx.y, b = blockIdx.x;
  int tid = threadIdx.x;
  int node0 = b * BW;
  int bb = bucketBase[g * NBUCK + b];
  int total = bucketCnt[g * NBUCK + b];
  const unsigned int* bp = binned + (size_t)g * NE + bb;
  for (int i = tid; i < BW; i += 256) {
    int node = node0 + i;
    cur[i] = (node < NN) ? rp[g * (NN + 1) + node] : 0;
  }
  __syncthreads();
  for (int e = tid; e < total; e += 256) {
    unsigned int p = bp[e];
    int srcid = (int)(p & 0xffffu);
    int r = atomicAdd(&cur[(int)(p >> 16) - node0], 1);
    colp[(size_t)g * NE + r] = packsw(srcid, dinv[g * NN + srcid]);
  }
}

// ---------------- fused 3-branch aggregation: 4x16-lane row groups ----------------
// Wave = 4 groups of 16 lanes. Group q handles edge slots j+u*4+q; lane covers
// features (lane&15)*8..+7 via one half8 (16B) load -> one quarter-wave per row.
// Slots beyond degree hold packed 0 (src 0, weight +0.0) -> no inner guards.

__global__ __launch_bounds__(256) void aggf_kernel(
    const __half* __restrict__ srch, const int* __restrict__ rp,
    const unsigned int* __restrict__ colp, const float* __restrict__ dinv,
    const int* __restrict__ index, __half* __restrict__ tout, int nrows) {
  int w = (blockIdx.x * 256 + threadIdx.x) >> 6;
  if (w >= nrows) return;
  int lane = threadIdx.x & 63;
  int q = lane >> 4;            // edge subgroup
  int fl = lane & 15;           // feature chunk: features fl*8 .. fl*8+7
  int node = index ? index[w] : w;
  const _Float16* srcv = (const _Float16*)srch;
  float di0 = dinv[node], di1 = dinv[NN + node], di2 = dinv[2 * NN + node];
  half8 selfh = *(const half8*)&srcv[(size_t)node * D + fl * 8];
  float a0[8], a1[8], a2[8];
#pragma unroll
  for (int k = 0; k < 8; k++) {
    float sv = (q == 0) ? (float)selfh[k] : 0.f;
    a0[k] = di0 * sv; a1[k] = di1 * sv; a2[k] = di2 * sv;
  }
  int s0 = rp[node],                e0 = rp[node + 1];
  int s1 = rp[(NN + 1) + node],     e1 = rp[(NN + 1) + node + 1];
  int s2 = rp[2 * (NN + 1) + node], e2 = rp[2 * (NN + 1) + node + 1];
  int n0 = e0 - s0, n1 = e1 - s1, n2 = e2 - s2;
  unsigned int c0 = (lane < n0) ? colp[s0 + lane] : 0u;
  unsigned int c1 = (lane < n1) ? colp[NE + s1 + lane] : 0u;
  unsigned int c2 = (lane < n2) ? colp[2 * NE + s2 + lane] : 0u;
  int m0 = min(n0, 64), m1 = min(n1, 64), m2 = min(n2, 64);
  int mx = max(m0, max(m1, m2));
  for (int j = 0; j < mx; j += 16) {
    bool p0 = j < m0, p1 = j < m1, p2 = j < m2;   // wave-uniform
    unsigned int v0[4], v1[4], v2[4];
    half8 h0[4], h1[4], h2[4];
    float w0[4], w1[4], w2[4];
    if (p0) {
#pragma unroll
      for (int u = 0; u < 4; u++) {
        v0[u] = (unsigned int)__shfl((int)c0, j + u * 4 + q, 64);
        w0[u] = wextract(v0[u]);
        h0[u] = *(const half8*)&srcv[(size_t)(v0[u] & 0xffffu) * D + fl * 8];
      }
    }
    if (p1) {
#pragma unroll
      for (int u = 0; u < 4; u++) {
        v1[u] = (unsigned int)__shfl((int)c1, j + u * 4 + q, 64);
        w1[u] = wextract(v1[u]);
        h1[u] = *(const half8*)&srcv[(size_t)(v1[u] & 0xffffu) * D + fl * 8];
      }
    }
    if (p2) {
#pragma unroll
      for (int u = 0; u < 4; u++) {
        v2[u] = (unsigned int)__shfl((int)c2, j + u * 4 + q, 64);
        w2[u] = wextract(v2[u]);
        h2[u] = *(const half8*)&srcv[(size_t)(v2[u] & 0xffffu) * D + fl * 8];
      }
    }
    if (p0) {
#pragma unroll
      for (int u = 0; u < 4; u++)
#pragma unroll
        for (int k = 0; k < 8; k++) a0[k] = fmaf((float)h0[u][k], w0[u], a0[k]);
    }
    if (p1) {
#pragma unroll
      for (int u = 0; u < 4; u++)
#pragma unroll
        for (int k = 0; k < 8; k++) a1[k] = fmaf((float)h1[u][k], w1[u], a1[k]);
    }
    if (p2) {
#pragma unroll
      for (int u = 0; u < 4; u++)
#pragma unroll
        for (int k = 0; k < 8; k++) a2[k] = fmaf((float)h2[u][k], w2[u], a2[k]);
    }
  }
  // rare tails (deg > 64); staged slots >= nn are 0 (weight +0.0)
  for (int p = s0 + 64; p < e0; p += 64) {
    int nn = min(e0 - p, 64);
    unsigned int c = (lane < nn) ? colp[p + lane] : 0u;
    for (int j = 0; j < nn; j += 4) {
      unsigned int v = (unsigned int)__shfl((int)c, j + q, 64);
      float wf = wextract(v);
      half8 hv = *(const half8*)&srcv[(size_t)(v & 0xffffu) * D + fl * 8];
#pragma unroll
      for (int k = 0; k < 8; k++) a0[k] = fmaf((float)hv[k], wf, a0[k]);
    }
  }
  for (int p = s1 + 64; p < e1; p += 64) {
    int nn = min(e1 - p, 64);
    unsigned int c = (lane < nn) ? colp[NE + p + lane] : 0u;
    for (int j = 0; j < nn; j += 4) {
      unsigned int v = (unsigned int)__shfl((int)c, j + q, 64);
      float wf = wextract(v);
      half8 hv = *(const half8*)&srcv[(size_t)(v & 0xffffu) * D + fl * 8];
#pragma unroll
      for (int k = 0; k < 8; k++) a1[k] = fmaf((float)hv[k], wf, a1[k]);
    }
  }
  for (int p = s2 + 64; p < e2; p += 64) {
    int nn = min(e2 - p, 64);
    unsigned int c = (lane < nn) ? colp[2 * NE + p + lane] : 0u;
    for (int j = 0; j < nn; j += 4) {
      unsigned int v = (unsigned int)__shfl((int)c, j + q, 64);
      float wf = wextract(v);
      half8 hv = *(const half8*)&srcv[(size_t)(v & 0xffffu) * D + fl * 8];
#pragma unroll
      for (int k = 0; k < 8; k++) a2[k] = fmaf((float)hv[k], wf, a2[k]);
    }
  }
  // reduce the 4 group partials
#pragma unroll
  for (int k = 0; k < 8; k++) {
    a0[k] += __shfl_xor(a0[k], 16, 64);
    a0[k] += __shfl_xor(a0[k], 32, 64);
    a1[k] += __shfl_xor(a1[k], 16, 64);
    a1[k] += __shfl_xor(a1[k], 32, 64);
    a2[k] += __shfl_xor(a2[k], 16, 64);
    a2[k] += __shfl_xor(a2[k], 32, 64);
  }
  if (q == 0) {
    size_t stride = (size_t)nrows * D;
    _Float16* tv = (_Float16*)tout;
    half8 o0, o1, o2;
#pragma unroll
    for (int k = 0; k < 8; k++) {
      o0[k] = (_Float16)(di0 * a0[k]);
      o1[k] = (_Float16)(di1 * a1[k]);
      o2[k] = (_Float16)(di2 * a2[k]);
    }
    *(half8*)&tv[(size_t)w * D + fl * 8]              = o0;
    *(half8*)&tv[stride + (size_t)w * D + fl * 8]     = o1;
    *(half8*)&tv[2 * stride + (size_t)w * D + fl * 8] = o2;
  }
}

// ---------------- fused 3-branch MFMA fp16 matmul + bias + relu + max ----------------
// A staged through LDS (coalesced global half8 loads, padded stride 136).

#define ALD 136   // padded LDS row stride (halves); 272B, 16B-aligned, conflict-light

__global__ __launch_bounds__(256) void mmf_kernel(const __half* __restrict__ A,
    const __half* __restrict__ Wf,
    const float* __restrict__ B0, const float* __restrict__ B1, const float* __restrict__ B2,
    __half* __restrict__ outh, float* __restrict__ outf, int M) {
  __shared__ _Float16 As[128 * ALD];  // 34.8 KB
  __shared__ _Float16 Ws[16384];      // 32 KB
  const float* Bb[3] = {B0, B1, B2};
  const int tid = threadIdx.x;
  const int wave = tid >> 6, lane = tid & 63;
  const int wr = (wave >> 1) * 64, wc = (wave & 1) * 64;
  const int ln = lane & 15, quad = lane >> 4;
  const int row0 = blockIdx.x * 128;
  float om[4][4][4];

  for (int b = 0; b < 3; b++) {
    const __half* Wb = Wf + (size_t)b * 16384;
#pragma unroll
    for (int i = 0; i < 8; i++) {
      int id = tid + i * 256;
      *(half8*)&Ws[id * 8] = *(const half8*)&Wb[(size_t)id * 8];
    }
    // stage A tile: 128 rows x 128 cols, coalesced
    const __half* Ab = A + (size_t)b * M * D;
#pragma unroll
    for (int i = 0; i < 8; i++) {
      int idx = tid + i * 256;          // 0..2047 half8 slots
      int r = idx >> 4, c8 = idx & 15;
      int gr = row0 + r;
      gr = (gr < M) ? gr : (M - 1);
      half8 v = *(const half8*)&Ab[(size_t)gr * D + c8 * 8];
      *(half8*)&As[r * ALD + c8 * 8] = v;
    }
    __syncthreads();

    float bias[4];
#pragma unroll
    for (int ct = 0; ct < 4; ct++) bias[ct] = Bb[b][wc + ct * 16 + ln];
    floatx4 acc[4][4];
#pragma unroll
    for (int rt = 0; rt < 4; rt++)
#pragma unroll
      for (int ct = 0; ct < 4; ct++)
        acc[rt][ct] = (floatx4){bias[ct], bias[ct], bias[ct], bias[ct]};

#pragma unroll
    for (int ks = 0; ks < 4; ks++) {
      half8 av[4];
#pragma unroll
      for (int rt = 0; rt < 4; rt++)
        av[rt] = *(const half8*)&As[(wr + rt * 16 + ln) * ALD + ks * 32 + quad * 8];
#pragma unroll
      for (int ct = 0; ct < 4; ct++) {
        int tt = (wc >> 4) + ct;
        half8 bv = *(const half8*)&Ws[((tt * 4 + ks) * 64 + lane) * 8];
#pragma unroll
        for (int rt = 0; rt < 4; rt++)
          acc[rt][ct] = __builtin_amdgcn_mfma_f32_16x16x32_f16(av[rt], bv, acc[rt][ct], 0, 0, 0);
      }
    }
#pragma unroll
    for (int rt = 0; rt < 4; rt++)
#pragma unroll
      for (int ct = 0; ct < 4; ct++)
#pragma unroll
        for (int r = 0; r < 4; r++) {
          float v = fmaxf(acc[rt][ct][r], 0.f);
          om[rt][ct][r] = (b == 0) ? v : fmaxf(om[rt][ct][r], v);
        }
    __syncthreads();
  }
#pragma unroll
  for (int rt = 0; rt < 4; rt++) {
    int m = row0 + wr + rt * 16 + quad * 4;
#pragma unroll
    for (int r = 0; r < 4; r++) {
      if (m + r < M) {
#pragma unroll
        for (int ct = 0; ct < 4; ct++) {
          int n = wc + ct * 16 + ln;
          if (outh) outh[(size_t)(m + r) * D + n] = __float2half(om[rt][ct][r]);
          else      outf[(size_t)(m + r) * D + n] = om[rt][ct][r];
        }
      }
    }
  }
}

// ---------------- launch ----------------

extern "C" void kernel_launch(void* const* d_in, const int* in_sizes, int n_in,
                              void* d_out, int out_size, void* d_ws, size_t ws_size,
                              hipStream_t stream) {
  const float* x = (const float*)d_in[0];
  const int* e0 = (const int*)d_in[1];
  const int* e1 = (const int*)d_in[2];
  const int* e2 = (const int*)d_in[3];
  const int* index = (const int*)d_in[4];
  const float* w1[3] = {(const float*)d_in[5], (const float*)d_in[9],  (const float*)d_in[13]};
  const float* b1[3] = {(const float*)d_in[6], (const float*)d_in[10], (const float*)d_in[14]};
  const float* w2[3] = {(const float*)d_in[7], (const float*)d_in[11], (const float*)d_in[15]};
  const float* b2[3] = {(const float*)d_in[8], (const float*)d_in[12], (const float*)d_in[16]};
  float* out = (float*)d_out;

  char* ws = (char*)d_ws;
  size_t o = 0;
  auto alloc = [&](size_t bytes) {
    o = (o + 255) & ~(size_t)255;
    void* p = ws + o;
    o += bytes;
    return p;
  };
  int*    rp     = (int*)alloc((size_t)NG * (NN + 1) * 4);
  unsigned int* colp = (unsigned int*)alloc((size_t)NG * NE * 4);
  float*  dinv   = (float*)alloc((size_t)NG * NN * 4);
  int*    bcnt   = (int*)alloc((size_t)NG * NBUCK * 4);
  int*    bbase  = (int*)alloc((size_t)NG * NBUCK * 4);
  int*    bcur   = (int*)alloc((size_t)NG * NBUCK * 4);
  __half* xh     = (__half*)alloc((size_t)NN * D * 2);        // 12.8 MB
  __half* Wf     = (__half*)alloc((size_t)6 * 128 * 128 * 2); // 196 KB
  __half* t1     = (__half*)alloc((size_t)NG * NN * D * 2);   // 38.4 MB
  __half* hacc   = (__half*)alloc((size_t)NN * D * 2);        // 12.8 MB
  unsigned int* binned = (unsigned int*)t1;  // alias: consumed by csr/fillp before aggf writes t1
  __half* t2     = t1;                       // alias: t1 free during layer 2
  (void)ws_size; (void)in_sizes; (void)n_in; (void)out_size;

  hipMemsetAsync(bcnt, 0, (size_t)NG * NBUCK * 4, stream);
  prep_kernel<<<XCVT_BLKS + WCVT_BLKS + CNT_BLKS, 256, 0, stream>>>(
      x, xh, w1[0], w1[1], w1[2], w2[0], w2[1], w2[2], Wf, e0, e1, e2, bcnt);
  bscan_kernel<<<1, 64, 0, stream>>>(bcnt, bbase, bcur, rp);
  bin_kernel<<<dim3(NBLK_BIN, NG), 256, 0, stream>>>(e0, e1, e2, bcur, binned);
  csr_kernel<<<dim3(NBUCK, NG), 256, 0, stream>>>(binned, bbase, bcnt, rp, dinv);
  fillp_kernel<<<dim3(NBUCK, NG), 256, 0, stream>>>(binned, bbase, bcnt, rp, dinv, colp);

  // layer 1: t1_b = Norm_b(xh);  hacc = max_b relu(t1_b @ W1_b + b1_b)   [fp16]
  aggf_kernel<<<(NN * 64 + 255) / 256, 256, 0, stream>>>(xh, rp, colp, dinv, nullptr, t1, NN);
  mmf_kernel<<<(NN + 127) / 128, 256, 0, stream>>>(t1, Wf, b1[0], b1[1], b1[2],
                                                   hacc, nullptr, NN);
  // layer 2: t2_b = Norm_b(hacc)[index];  out = max_b relu(t2_b @ W2_b + b2_b)
  aggf_kernel<<<(NI * 64 + 255) / 256, 256, 0, stream>>>(hacc, rp, colp, dinv, index, t2, NI);
  mmf_kernel<<<(NI + 127) / 128, 256, 0, stream>>>(t2, Wf + (size_t)3 * 16384,
                                                   b2[0], b2[1], b2[2], nullptr, out, NI);
}

// Round 8
// 283.673 us; speedup vs baseline: 1.0626x; 1.0626x over previous
//
#include <hip/hip_runtime.h>
#include <hip/hip_fp16.h>

#define NN 50000
#define NE 600000
#define NG 3
#define D  128
#define NI 4096
#define BW 1024                         // nodes per bucket
#define NBUCK 49                        // ceil(NN/BW)
#define EPT_BIN 16
#define EPB_BIN (256 * EPT_BIN)         // 4096 edges per block
#define NBLK_BIN ((NE + EPB_BIN - 1) / EPB_BIN)   // 147
#define XCVT_BLKS 3125                  // NN*D/8 threads, 8 floats each
#define WCVT_BLKS 48
#define CNT_BLKS (NBLK_BIN * NG)        // 441

typedef _Float16 half8 __attribute__((ext_vector_type(8)));
typedef _Float16 half4v __attribute__((ext_vector_type(4)));
typedef float floatx4 __attribute__((ext_vector_type(4)));

static __device__ __forceinline__ float wextract(unsigned int v) {
  unsigned short u = (unsigned short)(v >> 16);
  _Float16 h;
  __builtin_memcpy(&h, &u, 2);
  return (float)h;
}

static __device__ __forceinline__ unsigned int packsw(int s, float w) {
  _Float16 h = (_Float16)w;
  unsigned short u;
  __builtin_memcpy(&u, &h, 2);
  return (unsigned int)s | ((unsigned int)u << 16);
}

// ---------------- fused prep: xcvt + wcvt + count ----------------

__global__ __launch_bounds__(256) void prep_kernel(
    const float* __restrict__ x, __half* __restrict__ xh,
    const float* __restrict__ W0, const float* __restrict__ W1, const float* __restrict__ W2,
    const float* __restrict__ W3, const float* __restrict__ W4, const float* __restrict__ W5,
    __half* __restrict__ Wf,
    const int* __restrict__ e0, const int* __restrict__ e1, const int* __restrict__ e2,
    int* __restrict__ bucketCnt) {
  __shared__ int cnt[NBUCK];
  int blk = blockIdx.x;
  int tid = threadIdx.x;
  if (blk < XCVT_BLKS) {
    int i = blk * 256 + tid;
    size_t base = (size_t)i * 8;
    float4 v0 = *(const float4*)&x[base];
    float4 v1 = *(const float4*)&x[base + 4];
    half8 h;
    h[0] = (_Float16)v0.x; h[1] = (_Float16)v0.y; h[2] = (_Float16)v0.z; h[3] = (_Float16)v0.w;
    h[4] = (_Float16)v1.x; h[5] = (_Float16)v1.y; h[6] = (_Float16)v1.z; h[7] = (_Float16)v1.w;
    *(half8*)&xh[base] = h;
  } else if (blk < XCVT_BLKS + WCVT_BLKS) {
    const float* Wm[6] = {W0, W1, W2, W3, W4, W5};
    int t = (blk - XCVT_BLKS) * 256 + tid;     // 0 .. 6*2048-1
    int mat = t >> 11;
    int fr = (t >> 6) & 31;
    int lane = t & 63;
    int tt = fr >> 2, ks = fr & 3;
    int n = tt * 16 + (lane & 15);
    int kb = ks * 32 + (lane >> 4) * 8;
    const float* W = Wm[mat];
#pragma unroll
    for (int j = 0; j < 8; j++)
      Wf[(size_t)t * 8 + j] = __float2half(W[(kb + j) * 128 + n]);
  } else {
    int cb = blk - XCVT_BLKS - WCVT_BLKS;
    int g = cb / NBLK_BIN, eb = cb % NBLK_BIN;
    const int* ei = (g == 0) ? e0 : ((g == 1) ? e1 : e2);
    if (tid < NBUCK) cnt[tid] = 0;
    __syncthreads();
    int base = eb * EPB_BIN;
#pragma unroll
    for (int i = 0; i < EPT_BIN; i++) {
      int e = base + tid + i * 256;
      if (e < NE) atomicAdd(&cnt[ei[NE + e] >> 10], 1);
    }
    __syncthreads();
    if (tid < NBUCK) atomicAdd(&bucketCnt[g * NBUCK + tid], cnt[tid]);
  }
}

__global__ void bscan_kernel(const int* __restrict__ bucketCnt, int* __restrict__ bucketBase,
                             int* __restrict__ cursor, int* __restrict__ rp) {
  int g = threadIdx.x;
  if (g >= NG) return;
  int run = 0;
  for (int b = 0; b < NBUCK; b++) {
    int c = bucketCnt[g * NBUCK + b];
    bucketBase[g * NBUCK + b] = run;
    cursor[g * NBUCK + b] = run;
    run += c;
  }
  rp[g * (NN + 1) + NN] = NE;
}

// per-wave histograms to cut same-address LDS atomic serialization
__global__ __launch_bounds__(256) void bin_kernel(const int* __restrict__ e0,
    const int* __restrict__ e1, const int* __restrict__ e2,
    int* __restrict__ cursor, unsigned int* __restrict__ binned) {
  __shared__ int cnt[4][NBUCK];
  __shared__ int base[NBUCK];
  __shared__ int woff[4][NBUCK];
  int g = blockIdx.y;
  const int* ei = (g == 0) ? e0 : ((g == 1) ? e1 : e2);
  int tid = threadIdx.x;
  int wave = tid >> 6;
  if (tid < NBUCK) { cnt[0][tid] = 0; cnt[1][tid] = 0; cnt[2][tid] = 0; cnt[3][tid] = 0; }
  __syncthreads();
  int estart = blockIdx.x * EPB_BIN;
  int src[EPT_BIN], dst[EPT_BIN], rk[EPT_BIN];
#pragma unroll
  for (int i = 0; i < EPT_BIN; i++) {
    int e = estart + tid + i * 256;
    if (e < NE) {
      src[i] = ei[e];
      dst[i] = ei[NE + e];
      rk[i] = atomicAdd(&cnt[wave][dst[i] >> 10], 1);
    } else {
      rk[i] = -1;
    }
  }
  __syncthreads();
  if (tid < NBUCK) {
    int c0 = cnt[0][tid], c1 = cnt[1][tid], c2 = cnt[2][tid], c3 = cnt[3][tid];
    int total = c0 + c1 + c2 + c3;
    base[tid] = (total > 0) ? atomicAdd(&cursor[g * NBUCK + tid], total) : 0;
    woff[0][tid] = 0; woff[1][tid] = c0; woff[2][tid] = c0 + c1; woff[3][tid] = c0 + c1 + c2;
  }
  __syncthreads();
#pragma unroll
  for (int i = 0; i < EPT_BIN; i++) {
    if (rk[i] >= 0) {
      int b = dst[i] >> 10;
      binned[(size_t)g * NE + base[b] + woff[wave][b] + rk[i]] =
          (unsigned int)src[i] | ((unsigned int)dst[i] << 16);
    }
  }
}

// phase 1: per-bucket degree histogram -> rp (global row ptr) + dinv
__global__ __launch_bounds__(256) void csr_kernel(const unsigned int* __restrict__ binned,
    const int* __restrict__ bucketBase, const int* __restrict__ bucketCnt,
    int* __restrict__ rp, float* __restrict__ dinv) {
  __shared__ int deg[BW];
  __shared__ int wsum[4];
  int g = blockIdx.y, b = blockIdx.x;
  int tid = threadIdx.x;
  int node0 = b * BW;
  int bb = bucketBase[g * NBUCK + b];
  int total = bucketCnt[g * NBUCK + b];
  const unsigned int* bp = binned + (size_t)g * NE + bb;
  for (int i = tid; i < BW; i += 256) deg[i] = 0;
  __syncthreads();
  for (int e = tid; e < total; e += 256) {
    unsigned int p = bp[e];
    atomicAdd(&deg[(int)(p >> 16) - node0], 1);
  }
  __syncthreads();
  int d0 = deg[tid * 4], d1 = deg[tid * 4 + 1], d2 = deg[tid * 4 + 2], d3 = deg[tid * 4 + 3];
  int s = d0 + d1 + d2 + d3;
  int lane = tid & 63;
  int incl = s;
#pragma unroll
  for (int off = 1; off < 64; off <<= 1) {
    int n = __shfl_up(incl, off, 64);
    if (lane >= off) incl += n;
  }
  if (lane == 63) wsum[tid >> 6] = incl;
  __syncthreads();
  int wbase = 0;
#pragma unroll
  for (int w = 0; w < 4; w++)
    if (w < (tid >> 6)) wbase += wsum[w];
  int ex = wbase + incl - s;
  int exs[4] = {ex, ex + d0, ex + d0 + d1, ex + d0 + d1 + d2};
  int ds[4] = {d0, d1, d2, d3};
#pragma unroll
  for (int k = 0; k < 4; k++) {
    int node = node0 + tid * 4 + k;
    if (node < NN) {
      rp[g * (NN + 1) + node] = bb + exs[k];
      dinv[g * NN + node] = rsqrtf((float)ds[k] + 1.0f);   // deg incl. self loop
    }
  }
}

// phase 2: scatter packed (src | fp16(dinv[src])) into bucket-private col region
__global__ __launch_bounds__(256) void fillp_kernel(const unsigned int* __restrict__ binned,
    const int* __restrict__ bucketBase, const int* __restrict__ bucketCnt,
    const int* __restrict__ rp, const float* __restrict__ dinv,
    unsigned int* __restrict__ colp) {
  __shared__ int cur[BW];
  int g = blockIdx.y, b = blockIdx.x;
  int tid = threadIdx.x;
  int node0 = b * BW;
  int bb = bucketBase[g * NBUCK + b];
  int total = bucketCnt[g * NBUCK + b];
  const unsigned int* bp = binned + (size_t)g * NE + bb;
  for (int i = tid; i < BW; i += 256) {
    int node = node0 + i;
    cur[i] = (node < NN) ? rp[g * (NN + 1) + node] : 0;
  }
  __syncthreads();
  for (int e = tid; e < total; e += 256) {
    unsigned int p = bp[e];
    int srcid = (int)(p & 0xffffu);
    int r = atomicAdd(&cur[(int)(p >> 16) - node0], 1);
    colp[(size_t)g * NE + r] = packsw(srcid, dinv[g * NN + srcid]);
  }
}

// ---------------- fused 3-branch aggregation: 2 edges per wave-inst ----------------
// lanes 0-31 even slots, lanes 32-63 odd slots; each lane covers 4 features (half4).
// Slots beyond degree hold packed 0 (src 0, weight +0.0) -> no inner bounds checks.
// NOTE (R7 lesson): 4x16 grouping raised VGPR 44->72, occupancy 45->28%, dur +12us.
// This latency-bound kernel wants waves, not fewer instructions. Keep VGPR <= ~48.

__global__ __launch_bounds__(256) void aggf_kernel(
    const __half* __restrict__ srch, const int* __restrict__ rp,
    const unsigned int* __restrict__ colp, const float* __restrict__ dinv,
    const int* __restrict__ index, __half* __restrict__ tout, int nrows) {
  int w = (blockIdx.x * 256 + threadIdx.x) >> 6;
  if (w >= nrows) return;
  int lane = threadIdx.x & 63;
  int sub = lane >> 5;           // which edge of the pair this half-wave handles
  int fl = lane & 31;            // feature group: features fl*4 .. fl*4+3
  int node = index ? index[w] : w;
  const _Float16* srcv = (const _Float16*)srch;
  half4v selfh = *(const half4v*)&srcv[(size_t)node * D + fl * 4];
  float di0 = dinv[node], di1 = dinv[NN + node], di2 = dinv[2 * NN + node];
  float a0[4], a1[4], a2[4];
#pragma unroll
  for (int k = 0; k < 4; k++) {
    float sv = sub ? 0.f : (float)selfh[k];
    a0[k] = di0 * sv; a1[k] = di1 * sv; a2[k] = di2 * sv;
  }
  int s0 = rp[node],                e0 = rp[node + 1];
  int s1 = rp[(NN + 1) + node],     e1 = rp[(NN + 1) + node + 1];
  int s2 = rp[2 * (NN + 1) + node], e2 = rp[2 * (NN + 1) + node + 1];
  int n0 = e0 - s0, n1 = e1 - s1, n2 = e2 - s2;
  unsigned int c0 = (lane < n0) ? colp[s0 + lane] : 0u;
  unsigned int c1 = (lane < n1) ? colp[NE + s1 + lane] : 0u;
  unsigned int c2 = (lane < n2) ? colp[2 * NE + s2 + lane] : 0u;
  int m0 = min(n0, 64), m1 = min(n1, 64), m2 = min(n2, 64);
  int mx = max(m0, max(m1, m2));
  for (int j = 0; j < mx; j += 8) {
    half4v h0[4], h1[4], h2[4];
    float w0[4], w1[4], w2[4];
    bool p0 = j < m0, p1 = j < m1, p2 = j < m2;   // wave-uniform
    if (p0) {
#pragma unroll
      for (int u = 0; u < 4; u++) {
        unsigned int v = (unsigned int)__shfl((int)c0, j + u * 2 + sub, 64);
        w0[u] = wextract(v);
        h0[u] = *(const half4v*)&srcv[(size_t)(v & 0xffffu) * D + fl * 4];
      }
    }
    if (p1) {
#pragma unroll
      for (int u = 0; u < 4; u++) {
        unsigned int v = (unsigned int)__shfl((int)c1, j + u * 2 + sub, 64);
        w1[u] = wextract(v);
        h1[u] = *(const half4v*)&srcv[(size_t)(v & 0xffffu) * D + fl * 4];
      }
    }
    if (p2) {
#pragma unroll
      for (int u = 0; u < 4; u++) {
        unsigned int v = (unsigned int)__shfl((int)c2, j + u * 2 + sub, 64);
        w2[u] = wextract(v);
        h2[u] = *(const half4v*)&srcv[(size_t)(v & 0xffffu) * D + fl * 4];
      }
    }
    if (p0) {
#pragma unroll
      for (int u = 0; u < 4; u++)
#pragma unroll
        for (int k = 0; k < 4; k++) a0[k] = fmaf((float)h0[u][k], w0[u], a0[k]);
    }
    if (p1) {
#pragma unroll
      for (int u = 0; u < 4; u++)
#pragma unroll
        for (int k = 0; k < 4; k++) a1[k] = fmaf((float)h1[u][k], w1[u], a1[k]);
    }
    if (p2) {
#pragma unroll
      for (int u = 0; u < 4; u++)
#pragma unroll
        for (int k = 0; k < 4; k++) a2[k] = fmaf((float)h2[u][k], w2[u], a2[k]);
    }
  }
  // rare tails (deg > 64)
  for (int q = s0 + 64; q < e0; q += 64) {
    int nn = min(e0 - q, 64);
    unsigned int c = (lane < nn) ? colp[q + lane] : 0u;
    for (int j = 0; j < nn; j += 2) {
      unsigned int v = (unsigned int)__shfl((int)c, j + sub, 64);
      float wf = wextract(v);
      half4v hv = *(const half4v*)&srcv[(size_t)(v & 0xffffu) * D + fl * 4];
#pragma unroll
      for (int k = 0; k < 4; k++) a0[k] = fmaf((float)hv[k], wf, a0[k]);
    }
  }
  for (int q = s1 + 64; q < e1; q += 64) {
    int nn = min(e1 - q, 64);
    unsigned int c = (lane < nn) ? colp[NE + q + lane] : 0u;
    for (int j = 0; j < nn; j += 2) {
      unsigned int v = (unsigned int)__shfl((int)c, j + sub, 64);
      float wf = wextract(v);
      half4v hv = *(const half4v*)&srcv[(size_t)(v & 0xffffu) * D + fl * 4];
#pragma unroll
      for (int k = 0; k < 4; k++) a1[k] = fmaf((float)hv[k], wf, a1[k]);
    }
  }
  for (int q = s2 + 64; q < e2; q += 64) {
    int nn = min(e2 - q, 64);
    unsigned int c = (lane < nn) ? colp[2 * NE + q + lane] : 0u;
    for (int j = 0; j < nn; j += 2) {
      unsigned int v = (unsigned int)__shfl((int)c, j + sub, 64);
      float wf = wextract(v);
      half4v hv = *(const half4v*)&srcv[(size_t)(v & 0xffffu) * D + fl * 4];
#pragma unroll
      for (int k = 0; k < 4; k++) a2[k] = fmaf((float)hv[k], wf, a2[k]);
    }
  }
  // combine the two half-wave partial sums
#pragma unroll
  for (int k = 0; k < 4; k++) {
    a0[k] += __shfl_xor(a0[k], 32, 64);
    a1[k] += __shfl_xor(a1[k], 32, 64);
    a2[k] += __shfl_xor(a2[k], 32, 64);
  }
  if (sub == 0) {
    size_t stride = (size_t)nrows * D;
    _Float16* tv = (_Float16*)tout;
    half4v o0, o1, o2;
#pragma unroll
    for (int k = 0; k < 4; k++) {
      o0[k] = (_Float16)(di0 * a0[k]);
      o1[k] = (_Float16)(di1 * a1[k]);
      o2[k] = (_Float16)(di2 * a2[k]);
    }
    *(half4v*)&tv[(size_t)w * D + fl * 4]              = o0;
    *(half4v*)&tv[stride + (size_t)w * D + fl * 4]     = o1;
    *(half4v*)&tv[2 * stride + (size_t)w * D + fl * 4] = o2;
  }
}

// ---------------- fused 3-branch MFMA fp16 matmul + bias + relu + max ----------------
// A staged through LDS (coalesced global half8 loads, padded stride 136).

#define ALD 136   // padded LDS row stride (halves); 272B, 16B-aligned, conflict-light

__global__ __launch_bounds__(256) void mmf_kernel(const __half* __restrict__ A,
    const __half* __restrict__ Wf,
    const float* __restrict__ B0, const float* __restrict__ B1, const float* __restrict__ B2,
    __half* __restrict__ outh, float* __restrict__ outf, int M) {
  __shared__ _Float16 As[128 * ALD];  // 34.8 KB
  __shared__ _Float16 Ws[16384];      // 32 KB
  const float* Bb[3] = {B0, B1, B2};
  const int tid = threadIdx.x;
  const int wave = tid >> 6, lane = tid & 63;
  const int wr = (wave >> 1) * 64, wc = (wave & 1) * 64;
  const int ln = lane & 15, quad = lane >> 4;
  const int row0 = blockIdx.x * 128;
  float om[4][4][4];

  for (int b = 0; b < 3; b++) {
    const __half* Wb = Wf + (size_t)b * 16384;
#pragma unroll
    for (int i = 0; i < 8; i++) {
      int id = tid + i * 256;
      *(half8*)&Ws[id * 8] = *(const half8*)&Wb[(size_t)id * 8];
    }
    const __half* Ab = A + (size_t)b * M * D;
#pragma unroll
    for (int i = 0; i < 8; i++) {
      int idx = tid + i * 256;          // 0..2047 half8 slots
      int r = idx >> 4, c8 = idx & 15;
      int gr = row0 + r;
      gr = (gr < M) ? gr : (M - 1);
      half8 v = *(const half8*)&Ab[(size_t)gr * D + c8 * 8];
      *(half8*)&As[r * ALD + c8 * 8] = v;
    }
    __syncthreads();

    float bias[4];
#pragma unroll
    for (int ct = 0; ct < 4; ct++) bias[ct] = Bb[b][wc + ct * 16 + ln];
    floatx4 acc[4][4];
#pragma unroll
    for (int rt = 0; rt < 4; rt++)
#pragma unroll
      for (int ct = 0; ct < 4; ct++)
        acc[rt][ct] = (floatx4){bias[ct], bias[ct], bias[ct], bias[ct]};

#pragma unroll
    for (int ks = 0; ks < 4; ks++) {
      half8 av[4];
#pragma unroll
      for (int rt = 0; rt < 4; rt++)
        av[rt] = *(const half8*)&As[(wr + rt * 16 + ln) * ALD + ks * 32 + quad * 8];
#pragma unroll
      for (int ct = 0; ct < 4; ct++) {
        int tt = (wc >> 4) + ct;
        half8 bv = *(const half8*)&Ws[((tt * 4 + ks) * 64 + lane) * 8];
#pragma unroll
        for (int rt = 0; rt < 4; rt++)
          acc[rt][ct] = __builtin_amdgcn_mfma_f32_16x16x32_f16(av[rt], bv, acc[rt][ct], 0, 0, 0);
      }
    }
#pragma unroll
    for (int rt = 0; rt < 4; rt++)
#pragma unroll
      for (int ct = 0; ct < 4; ct++)
#pragma unroll
        for (int r = 0; r < 4; r++) {
          float v = fmaxf(acc[rt][ct][r], 0.f);
          om[rt][ct][r] = (b == 0) ? v : fmaxf(om[rt][ct][r], v);
        }
    __syncthreads();
  }
#pragma unroll
  for (int rt = 0; rt < 4; rt++) {
    int m = row0 + wr + rt * 16 + quad * 4;
#pragma unroll
    for (int r = 0; r < 4; r++) {
      if (m + r < M) {
#pragma unroll
        for (int ct = 0; ct < 4; ct++) {
          int n = wc + ct * 16 + ln;
          if (outh) outh[(size_t)(m + r) * D + n] = __float2half(om[rt][ct][r]);
          else      outf[(size_t)(m + r) * D + n] = om[rt][ct][r];
        }
      }
    }
  }
}

// ---------------- launch ----------------

extern "C" void kernel_launch(void* const* d_in, const int* in_sizes, int n_in,
                              void* d_out, int out_size, void* d_ws, size_t ws_size,
                              hipStream_t stream) {
  const float* x = (const float*)d_in[0];
  const int* e0 = (const int*)d_in[1];
  const int* e1 = (const int*)d_in[2];
  const int* e2 = (const int*)d_in[3];
  const int* index = (const int*)d_in[4];
  const float* w1[3] = {(const float*)d_in[5], (const float*)d_in[9],  (const float*)d_in[13]};
  const float* b1[3] = {(const float*)d_in[6], (const float*)d_in[10], (const float*)d_in[14]};
  const float* w2[3] = {(const float*)d_in[7], (const float*)d_in[11], (const float*)d_in[15]};
  const float* b2[3] = {(const float*)d_in[8], (const float*)d_in[12], (const float*)d_in[16]};
  float* out = (float*)d_out;

  char* ws = (char*)d_ws;
  size_t o = 0;
  auto alloc = [&](size_t bytes) {
    o = (o + 255) & ~(size_t)255;
    void* p = ws + o;
    o += bytes;
    return p;
  };
  int*    rp     = (int*)alloc((size_t)NG * (NN + 1) * 4);
  unsigned int* colp = (unsigned int*)alloc((size_t)NG * NE * 4);
  float*  dinv   = (float*)alloc((size_t)NG * NN * 4);
  int*    bcnt   = (int*)alloc((size_t)NG * NBUCK * 4);
  int*    bbase  = (int*)alloc((size_t)NG * NBUCK * 4);
  int*    bcur   = (int*)alloc((size_t)NG * NBUCK * 4);
  __half* xh     = (__half*)alloc((size_t)NN * D * 2);        // 12.8 MB
  __half* Wf     = (__half*)alloc((size_t)6 * 128 * 128 * 2); // 196 KB
  __half* t1     = (__half*)alloc((size_t)NG * NN * D * 2);   // 38.4 MB
  __half* hacc   = (__half*)alloc((size_t)NN * D * 2);        // 12.8 MB
  unsigned int* binned = (unsigned int*)t1;  // alias: consumed by csr/fillp before aggf writes t1
  __half* t2     = t1;                       // alias: t1 free during layer 2
  (void)ws_size; (void)in_sizes; (void)n_in; (void)out_size;

  hipMemsetAsync(bcnt, 0, (size_t)NG * NBUCK * 4, stream);
  prep_kernel<<<XCVT_BLKS + WCVT_BLKS + CNT_BLKS, 256, 0, stream>>>(
      x, xh, w1[0], w1[1], w1[2], w2[0], w2[1], w2[2], Wf, e0, e1, e2, bcnt);
  bscan_kernel<<<1, 64, 0, stream>>>(bcnt, bbase, bcur, rp);
  bin_kernel<<<dim3(NBLK_BIN, NG), 256, 0, stream>>>(e0, e1, e2, bcur, binned);
  csr_kernel<<<dim3(NBUCK, NG), 256, 0, stream>>>(binned, bbase, bcnt, rp, dinv);
  fillp_kernel<<<dim3(NBUCK, NG), 256, 0, stream>>>(binned, bbase, bcnt, rp, dinv, colp);

  // layer 1: t1_b = Norm_b(xh);  hacc = max_b relu(t1_b @ W1_b + b1_b)   [fp16]
  aggf_kernel<<<(NN * 64 + 255) / 256, 256, 0, stream>>>(xh, rp, colp, dinv, nullptr, t1, NN);
  mmf_kernel<<<(NN + 127) / 128, 256, 0, stream>>>(t1, Wf, b1[0], b1[1], b1[2],
                                                   hacc, nullptr, NN);
  // layer 2: t2_b = Norm_b(hacc)[index];  out = max_b relu(t2_b @ W2_b + b2_b)
  aggf_kernel<<<(NI * 64 + 255) / 256, 256, 0, stream>>>(hacc, rp, colp, dinv, index, t2, NI);
  mmf_kernel<<<(NI + 127) / 128, 256, 0, stream>>>(t2, Wf + (size_t)3 * 16384,
                                                   b2[0], b2[1], b2[2], nullptr, out, NI);
}

// Round 9
// 278.027 us; speedup vs baseline: 1.0842x; 1.0203x over previous
//
#include <hip/hip_runtime.h>
#include <hip/hip_fp16.h>

#define NN 50000
#define NE 600000
#define NG 3
#define D  128
#define NI 4096
#define BW 1024                         // nodes per bucket
#define NBUCK 49                        // ceil(NN/BW)
#define EPT_BIN 16
#define EPB_BIN (256 * EPT_BIN)         // 4096 edges per block
#define NBLK_BIN ((NE + EPB_BIN - 1) / EPB_BIN)   // 147
#define XCVT_BLKS 3125                  // NN*D/8 threads, 8 floats each
#define WCVT_BLKS 48
#define CNT_BLKS (NBLK_BIN * NG)        // 441

typedef _Float16 half8 __attribute__((ext_vector_type(8)));
typedef _Float16 half4v __attribute__((ext_vector_type(4)));
typedef float floatx4 __attribute__((ext_vector_type(4)));

static __device__ __forceinline__ float wextract(unsigned int v) {
  unsigned short u = (unsigned short)(v >> 16);
  _Float16 h;
  __builtin_memcpy(&h, &u, 2);
  return (float)h;
}

static __device__ __forceinline__ unsigned int packsw(int s, float w) {
  _Float16 h = (_Float16)w;
  unsigned short u;
  __builtin_memcpy(&u, &h, 2);
  return (unsigned int)s | ((unsigned int)u << 16);
}

// ---------------- fused prep: xcvt + wcvt + count ----------------

__global__ __launch_bounds__(256) void prep_kernel(
    const float* __restrict__ x, __half* __restrict__ xh,
    const float* __restrict__ W0, const float* __restrict__ W1, const float* __restrict__ W2,
    const float* __restrict__ W3, const float* __restrict__ W4, const float* __restrict__ W5,
    __half* __restrict__ Wf,
    const int* __restrict__ e0, const int* __restrict__ e1, const int* __restrict__ e2,
    int* __restrict__ bucketCnt) {
  __shared__ int cnt[NBUCK];
  int blk = blockIdx.x;
  int tid = threadIdx.x;
  if (blk < XCVT_BLKS) {
    int i = blk * 256 + tid;
    size_t base = (size_t)i * 8;
    float4 v0 = *(const float4*)&x[base];
    float4 v1 = *(const float4*)&x[base + 4];
    half8 h;
    h[0] = (_Float16)v0.x; h[1] = (_Float16)v0.y; h[2] = (_Float16)v0.z; h[3] = (_Float16)v0.w;
    h[4] = (_Float16)v1.x; h[5] = (_Float16)v1.y; h[6] = (_Float16)v1.z; h[7] = (_Float16)v1.w;
    *(half8*)&xh[base] = h;
  } else if (blk < XCVT_BLKS + WCVT_BLKS) {
    const float* Wm[6] = {W0, W1, W2, W3, W4, W5};
    int t = (blk - XCVT_BLKS) * 256 + tid;     // 0 .. 6*2048-1
    int mat = t >> 11;
    int fr = (t >> 6) & 31;
    int lane = t & 63;
    int tt = fr >> 2, ks = fr & 3;
    int n = tt * 16 + (lane & 15);
    int kb = ks * 32 + (lane >> 4) * 8;
    const float* W = Wm[mat];
#pragma unroll
    for (int j = 0; j < 8; j++)
      Wf[(size_t)t * 8 + j] = __float2half(W[(kb + j) * 128 + n]);
  } else {
    int cb = blk - XCVT_BLKS - WCVT_BLKS;
    int g = cb / NBLK_BIN, eb = cb % NBLK_BIN;
    const int* ei = (g == 0) ? e0 : ((g == 1) ? e1 : e2);
    if (tid < NBUCK) cnt[tid] = 0;
    __syncthreads();
    int base = eb * EPB_BIN;
#pragma unroll
    for (int i = 0; i < EPT_BIN; i++) {
      int e = base + tid + i * 256;
      if (e < NE) atomicAdd(&cnt[ei[NE + e] >> 10], 1);
    }
    __syncthreads();
    if (tid < NBUCK) atomicAdd(&bucketCnt[g * NBUCK + tid], cnt[tid]);
  }
}

// wave-parallel exclusive scan of 49 bucket counts per graph (was: serial 1-thread walk)
__global__ void bscan_kernel(const int* __restrict__ bucketCnt, int* __restrict__ bucketBase,
                             int* __restrict__ cursor, int* __restrict__ rp) {
  int g = threadIdx.x >> 6;
  int lane = threadIdx.x & 63;
  if (g >= NG) return;
  int v = (lane < NBUCK) ? bucketCnt[g * NBUCK + lane] : 0;
  int incl = v;
#pragma unroll
  for (int off = 1; off < 64; off <<= 1) {
    int t = __shfl_up(incl, off, 64);
    if (lane >= off) incl += t;
  }
  int ex = incl - v;
  if (lane < NBUCK) {
    bucketBase[g * NBUCK + lane] = ex;
    cursor[g * NBUCK + lane] = ex;
  }
  if (lane == 0) rp[g * (NN + 1) + NN] = NE;
}

// per-wave histograms to cut same-address LDS atomic serialization
__global__ __launch_bounds__(256) void bin_kernel(const int* __restrict__ e0,
    const int* __restrict__ e1, const int* __restrict__ e2,
    int* __restrict__ cursor, unsigned int* __restrict__ binned) {
  __shared__ int cnt[4][NBUCK];
  __shared__ int base[NBUCK];
  __shared__ int woff[4][NBUCK];
  int g = blockIdx.y;
  const int* ei = (g == 0) ? e0 : ((g == 1) ? e1 : e2);
  int tid = threadIdx.x;
  int wave = tid >> 6;
  if (tid < NBUCK) { cnt[0][tid] = 0; cnt[1][tid] = 0; cnt[2][tid] = 0; cnt[3][tid] = 0; }
  __syncthreads();
  int estart = blockIdx.x * EPB_BIN;
  int src[EPT_BIN], dst[EPT_BIN], rk[EPT_BIN];
#pragma unroll
  for (int i = 0; i < EPT_BIN; i++) {
    int e = estart + tid + i * 256;
    if (e < NE) {
      src[i] = ei[e];
      dst[i] = ei[NE + e];
      rk[i] = atomicAdd(&cnt[wave][dst[i] >> 10], 1);
    } else {
      rk[i] = -1;
    }
  }
  __syncthreads();
  if (tid < NBUCK) {
    int c0 = cnt[0][tid], c1 = cnt[1][tid], c2 = cnt[2][tid], c3 = cnt[3][tid];
    int total = c0 + c1 + c2 + c3;
    base[tid] = (total > 0) ? atomicAdd(&cursor[g * NBUCK + tid], total) : 0;
    woff[0][tid] = 0; woff[1][tid] = c0; woff[2][tid] = c0 + c1; woff[3][tid] = c0 + c1 + c2;
  }
  __syncthreads();
#pragma unroll
  for (int i = 0; i < EPT_BIN; i++) {
    if (rk[i] >= 0) {
      int b = dst[i] >> 10;
      binned[(size_t)g * NE + base[b] + woff[wave][b] + rk[i]] =
          (unsigned int)src[i] | ((unsigned int)dst[i] << 16);
    }
  }
}

// phase 1: per-bucket degree histogram -> rp (global row ptr) + dinv
__global__ __launch_bounds__(256) void csr_kernel(const unsigned int* __restrict__ binned,
    const int* __restrict__ bucketBase, const int* __restrict__ bucketCnt,
    int* __restrict__ rp, float* __restrict__ dinv) {
  __shared__ int deg[BW];
  __shared__ int wsum[4];
  int g = blockIdx.y, b = blockIdx.x;
  int tid = threadIdx.x;
  int node0 = b * BW;
  int bb = bucketBase[g * NBUCK + b];
  int total = bucketCnt[g * NBUCK + b];
  const unsigned int* bp = binned + (size_t)g * NE + bb;
  for (int i = tid; i < BW; i += 256) deg[i] = 0;
  __syncthreads();
  for (int e = tid; e < total; e += 256) {
    unsigned int p = bp[e];
    atomicAdd(&deg[(int)(p >> 16) - node0], 1);
  }
  __syncthreads();
  int d0 = deg[tid * 4], d1 = deg[tid * 4 + 1], d2 = deg[tid * 4 + 2], d3 = deg[tid * 4 + 3];
  int s = d0 + d1 + d2 + d3;
  int lane = tid & 63;
  int incl = s;
#pragma unroll
  for (int off = 1; off < 64; off <<= 1) {
    int n = __shfl_up(incl, off, 64);
    if (lane >= off) incl += n;
  }
  if (lane == 63) wsum[tid >> 6] = incl;
  __syncthreads();
  int wbase = 0;
#pragma unroll
  for (int w = 0; w < 4; w++)
    if (w < (tid >> 6)) wbase += wsum[w];
  int ex = wbase + incl - s;
  int exs[4] = {ex, ex + d0, ex + d0 + d1, ex + d0 + d1 + d2};
  int ds[4] = {d0, d1, d2, d3};
#pragma unroll
  for (int k = 0; k < 4; k++) {
    int node = node0 + tid * 4 + k;
    if (node < NN) {
      rp[g * (NN + 1) + node] = bb + exs[k];
      dinv[g * NN + node] = rsqrtf((float)ds[k] + 1.0f);   // deg incl. self loop
    }
  }
}

// phase 2: scatter packed (src | fp16(dinv[src])) into bucket-private col region
__global__ __launch_bounds__(256) void fillp_kernel(const unsigned int* __restrict__ binned,
    const int* __restrict__ bucketBase, const int* __restrict__ bucketCnt,
    const int* __restrict__ rp, const float* __restrict__ dinv,
    unsigned int* __restrict__ colp) {
  __shared__ int cur[BW];
  int g = blockIdx.y, b = blockIdx.x;
  int tid = threadIdx.x;
  int node0 = b * BW;
  int bb = bucketBase[g * NBUCK + b];
  int total = bucketCnt[g * NBUCK + b];
  const unsigned int* bp = binned + (size_t)g * NE + bb;
  for (int i = tid; i < BW; i += 256) {
    int node = node0 + i;
    cur[i] = (node < NN) ? rp[g * (NN + 1) + node] : 0;
  }
  __syncthreads();
  for (int e = tid; e < total; e += 256) {
    unsigned int p = bp[e];
    int srcid = (int)(p & 0xffffu);
    int r = atomicAdd(&cur[(int)(p >> 16) - node0], 1);
    colp[(size_t)g * NE + r] = packsw(srcid, dinv[g * NN + srcid]);
  }
}

// ---------------- aggregation: one wave per (node, branch) ----------------
// blockIdx.y = branch. Lanes 0-31 even edge slots, 32-63 odd; lane covers 4 features.
// Slots beyond degree hold packed 0 (src 0, weight +0.0) -> no inner bounds checks.
// NOTE (R7 lesson): keep VGPR low — this kernel is latency-bound and wants waves.
// R9: split branches across waves (was 3 branches/wave): no max-degree coupling,
// VGPR 44->~36, 3x wave count (esp. layer 2: 256 -> 768+ blocks).

__global__ __launch_bounds__(256) void aggb_kernel(
    const __half* __restrict__ srch, const int* __restrict__ rp,
    const unsigned int* __restrict__ colp, const float* __restrict__ dinv,
    const int* __restrict__ index, __half* __restrict__ tout, int nrows) {
  int b = blockIdx.y;
  int w = (blockIdx.x * 256 + threadIdx.x) >> 6;
  if (w >= nrows) return;
  int lane = threadIdx.x & 63;
  int sub = lane >> 5;           // which edge of the pair this half-wave handles
  int fl = lane & 31;            // feature group: features fl*4 .. fl*4+3
  int node = index ? index[w] : w;
  const _Float16* srcv = (const _Float16*)srch;
  half4v selfh = *(const half4v*)&srcv[(size_t)node * D + fl * 4];
  float di = dinv[b * NN + node];
  float a[4];
#pragma unroll
  for (int k = 0; k < 4; k++) a[k] = sub ? 0.f : di * (float)selfh[k];
  const int* rpb = rp + b * (NN + 1);
  int s = rpb[node], e = rpb[node + 1];
  int n = e - s;
  const unsigned int* cp = colp + (size_t)b * NE;
  unsigned int c = (lane < n) ? cp[s + lane] : 0u;
  int m = min(n, 64);
  for (int j = 0; j < m; j += 8) {
    half4v h[4];
    float wg[4];
#pragma unroll
    for (int u = 0; u < 4; u++) {
      unsigned int v = (unsigned int)__shfl((int)c, j + u * 2 + sub, 64);
      wg[u] = wextract(v);
      h[u] = *(const half4v*)&srcv[(size_t)(v & 0xffffu) * D + fl * 4];
    }
#pragma unroll
    for (int u = 0; u < 4; u++)
#pragma unroll
      for (int k = 0; k < 4; k++) a[k] = fmaf((float)h[u][k], wg[u], a[k]);
  }
  // rare tail (deg > 64)
  for (int q = s + 64; q < e; q += 64) {
    int nn = min(e - q, 64);
    unsigned int cc = (lane < nn) ? cp[q + lane] : 0u;
    for (int j = 0; j < nn; j += 2) {
      unsigned int v = (unsigned int)__shfl((int)cc, j + sub, 64);
      float wf = wextract(v);
      half4v hv = *(const half4v*)&srcv[(size_t)(v & 0xffffu) * D + fl * 4];
#pragma unroll
      for (int k = 0; k < 4; k++) a[k] = fmaf((float)hv[k], wf, a[k]);
    }
  }
#pragma unroll
  for (int k = 0; k < 4; k++) a[k] += __shfl_xor(a[k], 32, 64);
  if (sub == 0) {
    half4v o;
#pragma unroll
    for (int k = 0; k < 4; k++) o[k] = (_Float16)(di * a[k]);
    _Float16* tv = (_Float16*)tout;
    *(half4v*)&tv[(size_t)b * nrows * D + (size_t)w * D + fl * 4] = o;
  }
}

// ---------------- fused 3-branch MFMA fp16 matmul + bias + relu + max ----------------
// A staged through LDS (coalesced global half8 loads, padded stride 136).

#define ALD 136   // padded LDS row stride (halves); 272B, 16B-aligned, conflict-light

__global__ __launch_bounds__(256) void mmf_kernel(const __half* __restrict__ A,
    const __half* __restrict__ Wf,
    const float* __restrict__ B0, const float* __restrict__ B1, const float* __restrict__ B2,
    __half* __restrict__ outh, float* __restrict__ outf, int M) {
  __shared__ _Float16 As[128 * ALD];  // 34.8 KB
  __shared__ _Float16 Ws[16384];      // 32 KB
  const float* Bb[3] = {B0, B1, B2};
  const int tid = threadIdx.x;
  const int wave = tid >> 6, lane = tid & 63;
  const int wr = (wave >> 1) * 64, wc = (wave & 1) * 64;
  const int ln = lane & 15, quad = lane >> 4;
  const int row0 = blockIdx.x * 128;
  float om[4][4][4];

  for (int b = 0; b < 3; b++) {
    const __half* Wb = Wf + (size_t)b * 16384;
#pragma unroll
    for (int i = 0; i < 8; i++) {
      int id = tid + i * 256;
      *(half8*)&Ws[id * 8] = *(const half8*)&Wb[(size_t)id * 8];
    }
    const __half* Ab = A + (size_t)b * M * D;
#pragma unroll
    for (int i = 0; i < 8; i++) {
      int idx = tid + i * 256;          // 0..2047 half8 slots
      int r = idx >> 4, c8 = idx & 15;
      int gr = row0 + r;
      gr = (gr < M) ? gr : (M - 1);
      half8 v = *(const half8*)&Ab[(size_t)gr * D + c8 * 8];
      *(half8*)&As[r * ALD + c8 * 8] = v;
    }
    __syncthreads();

    float bias[4];
#pragma unroll
    for (int ct = 0; ct < 4; ct++) bias[ct] = Bb[b][wc + ct * 16 + ln];
    floatx4 acc[4][4];
#pragma unroll
    for (int rt = 0; rt < 4; rt++)
#pragma unroll
      for (int ct = 0; ct < 4; ct++)
        acc[rt][ct] = (floatx4){bias[ct], bias[ct], bias[ct], bias[ct]};

#pragma unroll
    for (int ks = 0; ks < 4; ks++) {
      half8 av[4];
#pragma unroll
      for (int rt = 0; rt < 4; rt++)
        av[rt] = *(const half8*)&As[(wr + rt * 16 + ln) * ALD + ks * 32 + quad * 8];
#pragma unroll
      for (int ct = 0; ct < 4; ct++) {
        int tt = (wc >> 4) + ct;
        half8 bv = *(const half8*)&Ws[((tt * 4 + ks) * 64 + lane) * 8];
#pragma unroll
        for (int rt = 0; rt < 4; rt++)
          acc[rt][ct] = __builtin_amdgcn_mfma_f32_16x16x32_f16(av[rt], bv, acc[rt][ct], 0, 0, 0);
      }
    }
#pragma unroll
    for (int rt = 0; rt < 4; rt++)
#pragma unroll
      for (int ct = 0; ct < 4; ct++)
#pragma unroll
        for (int r = 0; r < 4; r++) {
          float v = fmaxf(acc[rt][ct][r], 0.f);
          om[rt][ct][r] = (b == 0) ? v : fmaxf(om[rt][ct][r], v);
        }
    __syncthreads();
  }
#pragma unroll
  for (int rt = 0; rt < 4; rt++) {
    int m = row0 + wr + rt * 16 + quad * 4;
#pragma unroll
    for (int r = 0; r < 4; r++) {
      if (m + r < M) {
#pragma unroll
        for (int ct = 0; ct < 4; ct++) {
          int n = wc + ct * 16 + ln;
          if (outh) outh[(size_t)(m + r) * D + n] = __float2half(om[rt][ct][r]);
          else      outf[(size_t)(m + r) * D + n] = om[rt][ct][r];
        }
      }
    }
  }
}

// ---------------- launch ----------------

extern "C" void kernel_launch(void* const* d_in, const int* in_sizes, int n_in,
                              void* d_out, int out_size, void* d_ws, size_t ws_size,
                              hipStream_t stream) {
  const float* x = (const float*)d_in[0];
  const int* e0 = (const int*)d_in[1];
  const int* e1 = (const int*)d_in[2];
  const int* e2 = (const int*)d_in[3];
  const int* index = (const int*)d_in[4];
  const float* w1[3] = {(const float*)d_in[5], (const float*)d_in[9],  (const float*)d_in[13]};
  const float* b1[3] = {(const float*)d_in[6], (const float*)d_in[10], (const float*)d_in[14]};
  const float* w2[3] = {(const float*)d_in[7], (const float*)d_in[11], (const float*)d_in[15]};
  const float* b2[3] = {(const float*)d_in[8], (const float*)d_in[12], (const float*)d_in[16]};
  float* out = (float*)d_out;

  char* ws = (char*)d_ws;
  size_t o = 0;
  auto alloc = [&](size_t bytes) {
    o = (o + 255) & ~(size_t)255;
    void* p = ws + o;
    o += bytes;
    return p;
  };
  int*    rp     = (int*)alloc((size_t)NG * (NN + 1) * 4);
  unsigned int* colp = (unsigned int*)alloc((size_t)NG * NE * 4);
  float*  dinv   = (float*)alloc((size_t)NG * NN * 4);
  int*    bcnt   = (int*)alloc((size_t)NG * NBUCK * 4);
  int*    bbase  = (int*)alloc((size_t)NG * NBUCK * 4);
  int*    bcur   = (int*)alloc((size_t)NG * NBUCK * 4);
  __half* xh     = (__half*)alloc((size_t)NN * D * 2);        // 12.8 MB
  __half* Wf     = (__half*)alloc((size_t)6 * 128 * 128 * 2); // 196 KB
  __half* t1     = (__half*)alloc((size_t)NG * NN * D * 2);   // 38.4 MB
  __half* hacc   = (__half*)alloc((size_t)NN * D * 2);        // 12.8 MB
  unsigned int* binned = (unsigned int*)t1;  // alias: consumed by csr/fillp before aggb writes t1
  __half* t2     = t1;                       // alias: t1 free during layer 2
  (void)ws_size; (void)in_sizes; (void)n_in; (void)out_size;

  hipMemsetAsync(bcnt, 0, (size_t)NG * NBUCK * 4, stream);
  prep_kernel<<<XCVT_BLKS + WCVT_BLKS + CNT_BLKS, 256, 0, stream>>>(
      x, xh, w1[0], w1[1], w1[2], w2[0], w2[1], w2[2], Wf, e0, e1, e2, bcnt);
  bscan_kernel<<<1, 192, 0, stream>>>(bcnt, bbase, bcur, rp);
  bin_kernel<<<dim3(NBLK_BIN, NG), 256, 0, stream>>>(e0, e1, e2, bcur, binned);
  csr_kernel<<<dim3(NBUCK, NG), 256, 0, stream>>>(binned, bbase, bcnt, rp, dinv);
  fillp_kernel<<<dim3(NBUCK, NG), 256, 0, stream>>>(binned, bbase, bcnt, rp, dinv, colp);

  // layer 1: t1_b = Norm_b(xh);  hacc = max_b relu(t1_b @ W1_b + b1_b)   [fp16]
  aggb_kernel<<<dim3((NN * 64 + 255) / 256, NG), 256, 0, stream>>>(
      xh, rp, colp, dinv, nullptr, t1, NN);
  mmf_kernel<<<(NN + 127) / 128, 256, 0, stream>>>(t1, Wf, b1[0], b1[1], b1[2],
                                                   hacc, nullptr, NN);
  // layer 2: t2_b = Norm_b(hacc)[index];  out = max_b relu(t2_b @ W2_b + b2_b)
  aggb_kernel<<<dim3((NI * 64 + 255) / 256, NG), 256, 0, stream>>>(
      hacc, rp, colp, dinv, index, t2, NI);
  mmf_kernel<<<(NI + 127) / 128, 256, 0, stream>>>(t2, Wf + (size_t)3 * 16384,
                                                   b2[0], b2[1], b2[2], nullptr, out, NI);
}